// Round 3
// baseline (136.840 us; speedup 1.0000x reference)
//
#include <hip/hip_runtime.h>
#include <hip/hip_fp16.h>

typedef _Float16 h2 __attribute__((ext_vector_type(2)));
typedef float f2 __attribute__((ext_vector_type(2)));

#define NCH   1024      // chunks
#define CL    256       // outputs per chunk
#define HALO  96        // warm-up steps (contraction kills init error)
#define NBLK  44        // (HALO+CL)/8 blocks of 8 steps
#define TROW  141       // LDS trajectory row stride in dwords (odd -> conflict-free)

#if __has_builtin(__builtin_amdgcn_exp2f)
#define EXP2F __builtin_amdgcn_exp2f
#else
#define EXP2F exp2f
#endif
#if __has_builtin(__builtin_amdgcn_rcpf)
#define RCPF __builtin_amdgcn_rcpf
#else
#define RCPF(x) (1.0f / (x))
#endif

#define A_K   (-14.4269504088896341f)   /* -10*log2(e) */
#define UPC_K (7.21347520444481704f)    /* -A_K*0.5    */
#define K2_K  (2.8853900817779268f)     /* 2*log2(e)   */

// packed cvt: two f32 -> one dword of two f16 (bit_cast fixes __fp16/_Float16 type clash)
__device__ __forceinline__ h2 pkrtz(float a, float b) {
    return __builtin_bit_cast(h2, __builtin_amdgcn_cvt_pkrtz(a, b));
}

// w <- sigmoid(10*(w + u - 0.5)) == rcp(1 + exp2(A*w + up)), up = A*(u-0.5)
__device__ __forceinline__ float sigstep(float w, float up) {
    return RCPF(1.0f + EXP2F(__builtin_fmaf(A_K, w, up)));
}

__device__ __forceinline__ uint32_t pk16(float a, float b) {
    return __builtin_bit_cast(uint32_t, pkrtz(a, b));
}

__device__ __forceinline__ h2 ldw(uint32_t v) {
    return __builtin_bit_cast(h2, v);
}

// tanh(z) = 1 - 2/(exp2(K2*z)+1), elementwise on a packed pair
__device__ __forceinline__ h2 tanh2(h2 a) {
    float z0 = (float)a[0], z1 = (float)a[1];
    float t0 = 1.0f - 2.0f * RCPF(1.0f + EXP2F(K2_K * z0));
    float t1 = 1.0f - 2.0f * RCPF(1.0f + EXP2F(K2_K * z1));
    return pkrtz(t0, t1);
}

__global__ void __launch_bounds__(64)
fastnet_kernel(const float* __restrict__ x, const float* __restrict__ u,
               const float* __restrict__ W1, const float* __restrict__ W2,
               const float* __restrict__ W3, float* __restrict__ out) {
    __shared__ uint32_t traj[64 * TROW];   // 36.1 KB -> 4 wg/CU, grid fully resident

    const int  lane  = threadIdx.x;
    const int  ch    = blockIdx.x;
    const long cbase = (long)ch * CL;
    const float* su  = u + (cbase - HALO) * 140;  // never dereferenced below index 0

    // ---- initial weights: chunk 0 exact, others arbitrary (halo converges) ----
    float wa, wb, wc;
    if (ch == 0) {
        wa = (lane < 30) ? W1[lane] : (lane < 130 ? W2[lane - 30] : W3[lane - 130]);
        wb = W2[lane + 34];                                   // elems 64..127 all in W2
        int kc = lane + 128;
        wc = (lane < 12) ? ((kc < 130) ? W2[kc - 30] : W3[kc - 130]) : 0.5f;
    } else {
        wa = wb = wc = 0.5f;
    }

    float uA0[8], uA1[8], uA2[8], uB0[8], uB1[8], uB2[8];
    const int bstart = (ch == 0) ? (HALO / 8) : 0;

    // load block B_ of 8 steps; pre-fold u' = A*(u-0.5) off the critical chain
#define LOADBLK(B_, U0, U1, U2) do {                                            \
        const float* p_ = su + (long)(B_) * 8 * 140 + lane;                     \
        _Pragma("unroll")                                                       \
        for (int t = 0; t < 8; t++) {                                           \
            U0[t] = __builtin_fmaf(A_K, p_[t * 140      ], UPC_K);              \
            U1[t] = __builtin_fmaf(A_K, p_[t * 140 +  64], UPC_K);              \
            U2[t] = (lane < 12) ? __builtin_fmaf(A_K, p_[t * 140 + 128], UPC_K) \
                                : 0.0f;                                         \
        }                                                                       \
    } while (0)

    // run 8 recurrence steps; store fp16-packed step-pairs into LDS when in output region
#define COMPBLK(B_, U0, U1, U2) do {                                            \
        const int i0_ = (B_) * 8;                                               \
        uint32_t* trow_ = &traj[(((i0_ - HALO) & 127) >> 1) * TROW + lane];     \
        _Pragma("unroll")                                                       \
        for (int t = 0; t < 8; t += 2) {                                        \
            wa = sigstep(wa, U0[t]);   wb = sigstep(wb, U1[t]);                 \
            wc = sigstep(wc, U2[t]);                                            \
            float wa0 = wa, wb0 = wb, wc0 = wc;                                 \
            wa = sigstep(wa, U0[t+1]); wb = sigstep(wb, U1[t+1]);               \
            wc = sigstep(wc, U2[t+1]);                                          \
            if (i0_ >= HALO) {                                                  \
                uint32_t* tw_ = trow_ + (t >> 1) * TROW;                        \
                tw_[0]  = pk16(wa0, wa);                                        \
                tw_[64] = pk16(wb0, wb);                                        \
                if (lane < 12) tw_[128] = pk16(wc0, wc);                        \
            }                                                                   \
        }                                                                       \
    } while (0)

    // evaluate 2 steps' MLPs per lane with packed f16 math (lo=even step, hi=odd step)
#define DO_PHASEB(R_) do {                                                      \
        long g0_ = cbase + (long)(R_) * 128 + 2 * lane;                         \
        const uint32_t* tr_ = &traj[lane * TROW];                               \
        const float* xp_ = x + g0_ * 3;                                         \
        h2 xq0 = pkrtz(xp_[0], xp_[3]);                                         \
        h2 xq1 = pkrtz(xp_[1], xp_[4]);                                         \
        h2 xq2 = pkrtz(xp_[2], xp_[5]);                                         \
        h2 h1[10];                                                              \
        _Pragma("unroll")                                                       \
        for (int cc = 0; cc < 10; cc++) {                                       \
            h2 acc = ldw(tr_[cc]) * xq0;                                        \
            acc += ldw(tr_[10 + cc]) * xq1;                                     \
            acc += ldw(tr_[20 + cc]) * xq2;                                     \
            h1[cc] = tanh2(acc);                                                \
        }                                                                       \
        h2 hh[10];                                                              \
        _Pragma("unroll")                                                       \
        for (int cc = 0; cc < 10; cc++) {                                       \
            h2 acc = h1[0] * ldw(tr_[30 + cc]);                                 \
            _Pragma("unroll")                                                   \
            for (int r2 = 1; r2 < 10; r2++)                                     \
                acc += h1[r2] * ldw(tr_[30 + r2 * 10 + cc]);                    \
            hh[cc] = tanh2(acc);                                                \
        }                                                                       \
        h2 ya = hh[0] * ldw(tr_[130]);                                          \
        _Pragma("unroll")                                                       \
        for (int r2 = 1; r2 < 10; r2++) ya += hh[r2] * ldw(tr_[130 + r2]);      \
        f2 o_; o_[0] = (float)ya[0]; o_[1] = (float)ya[1];                      \
        *reinterpret_cast<f2*>(out + g0_) = o_;                                 \
    } while (0)

    LOADBLK(bstart, uA0, uA1, uA2);
    for (int b = bstart; b < NBLK; b += 2) {
        LOADBLK(b + 1, uB0, uB1, uB2);          // prefetch next block
        COMPBLK(b, uA0, uA1, uA2);
        if (b + 2 < NBLK) LOADBLK(b + 2, uA0, uA1, uA2);
        COMPBLK(b + 1, uB0, uB1, uB2);
        if (b + 1 == 27)        DO_PHASEB(0);   // outputs [cbase, cbase+128)
        if (b + 1 == NBLK - 1)  DO_PHASEB(1);   // outputs [cbase+128, cbase+256)
    }

#undef LOADBLK
#undef COMPBLK
#undef DO_PHASEB
}

extern "C" void kernel_launch(void* const* d_in, const int* in_sizes, int n_in,
                              void* d_out, int out_size, void* d_ws, size_t ws_size,
                              hipStream_t stream) {
    const float* x  = (const float*)d_in[0];
    const float* u  = (const float*)d_in[1];
    const float* W1 = (const float*)d_in[2];
    const float* W2 = (const float*)d_in[3];
    const float* W3 = (const float*)d_in[4];
    float* out = (float*)d_out;

    hipLaunchKernelGGL(fastnet_kernel, dim3(NCH), dim3(64), 0, stream,
                       x, u, W1, W2, W3, out);
}

// Round 4
// 42.270 us; speedup vs baseline: 3.2373x; 3.2373x over previous
//
#include <hip/hip_runtime.h>
#include <hip/hip_fp16.h>

typedef _Float16 h2 __attribute__((ext_vector_type(2)));
typedef float f2 __attribute__((ext_vector_type(2)));

#define NCH   1024                 // chunks (one single-wave workgroup each)
#define CL    256                  // outputs per chunk
#define HALO  64                   // warm-up steps (contraction ~e^-365: safe)
#define SPB   16                   // steps per staged block
#define NB    ((HALO + CL) / SPB)  // 20 blocks
#define UBUF_DW (SPB * 140)        // 2240 dwords = 8x w16 + 3x w4 issues exactly
#define TROW  141                  // traj row stride (odd -> conflict-free)
#define NROWS 32                   // pair-rows per phase-B round (64 steps)

#if __has_builtin(__builtin_amdgcn_exp2f)
#define EXP2F __builtin_amdgcn_exp2f
#else
#define EXP2F exp2f
#endif
#if __has_builtin(__builtin_amdgcn_rcpf)
#define RCPF __builtin_amdgcn_rcpf
#else
#define RCPF(x) (1.0f / (x))
#endif

#define A_K   (-14.4269504088896341f)   /* -10*log2(e) */
#define UPC_K (7.21347520444481704f)    /* -A_K*0.5    */
#define K2_K  (2.8853900817779268f)     /* 2*log2(e)   */

__device__ __forceinline__ h2 pkrtz(float a, float b) {
    return __builtin_bit_cast(h2, __builtin_amdgcn_cvt_pkrtz(a, b));
}
__device__ __forceinline__ float sigstep(float w, float up) {
    return RCPF(1.0f + EXP2F(__builtin_fmaf(A_K, w, up)));
}
__device__ __forceinline__ float fold(float u) {
    return __builtin_fmaf(A_K, u, UPC_K);
}
__device__ __forceinline__ uint32_t pk16(float a, float b) {
    return __builtin_bit_cast(uint32_t, pkrtz(a, b));
}
__device__ __forceinline__ h2 ldw(uint32_t v) {
    return __builtin_bit_cast(h2, v);
}
__device__ __forceinline__ h2 tanh2(h2 a) {
    float z0 = (float)a[0], z1 = (float)a[1];
    float t0 = 1.0f - 2.0f * RCPF(1.0f + EXP2F(K2_K * z0));
    float t1 = 1.0f - 2.0f * RCPF(1.0f + EXP2F(K2_K * z1));
    return pkrtz(t0, t1);
}

// async global->LDS: lane i's 16B/4B lands at ldsbase + i*size (linear)
__device__ __forceinline__ void gload_lds16(const float* g, float* l) {
    __builtin_amdgcn_global_load_lds(
        (__attribute__((address_space(1))) void*)(void*)g,
        (__attribute__((address_space(3))) void*)(void*)l, 16, 0, 0);
}
__device__ __forceinline__ void gload_lds4(const float* g, float* l) {
    __builtin_amdgcn_global_load_lds(
        (__attribute__((address_space(1))) void*)(void*)g,
        (__attribute__((address_space(3))) void*)(void*)l, 4, 0, 0);
}

#define WAITVM11 asm volatile("s_waitcnt vmcnt(11)" ::: "memory")
#define WAITVM0  asm volatile("s_waitcnt vmcnt(0)"  ::: "memory")
#define WAITLGKM asm volatile("s_waitcnt lgkmcnt(0)" ::: "memory")

__global__ void __launch_bounds__(64)
fastnet_kernel(const float* __restrict__ x, const float* __restrict__ u,
               const float* __restrict__ W1, const float* __restrict__ W2,
               const float* __restrict__ W3, float* __restrict__ out) {
    __shared__ float    ubuf[2][UBUF_DW];     // 17.9 KB staged u, double-buffered
    __shared__ uint32_t traj[NROWS * TROW];   // 18.0 KB fp16 weight trajectory

    const int  lane  = threadIdx.x;
    const int  ch    = blockIdx.x;
    const long cbase = (long)ch * CL;
    const float* su  = u + (cbase - (long)HALO) * 140;

    // ---- initial weights: chunk 0 exact, others converge through the halo ----
    float wa, wb, wc;
    if (ch == 0) {
        wa = (lane < 30) ? W1[lane] : (lane < 130 ? W2[lane - 30] : W3[lane - 130]);
        wb = W2[lane + 34];
        int kc = lane + 128;
        wc = (lane < 12) ? ((kc < 130) ? W2[kc - 30] : W3[kc - 130]) : 0.5f;
    } else {
        wa = wb = wc = 0.5f;
    }

    // stage one 16-step block of u into LDS buffer BUF_ (11 async issues)
#define STAGE(BUF_, B_) do {                                                    \
        const float* s_ = su + (long)(B_) * UBUF_DW;                            \
        float* d_ = &ubuf[BUF_][0];                                             \
        _Pragma("unroll")                                                       \
        for (int i_ = 0; i_ < 8; i_++)                                          \
            gload_lds16(s_ + i_ * 256 + lane * 4, d_ + i_ * 256);               \
        _Pragma("unroll")                                                       \
        for (int j_ = 0; j_ < 3; j_++)                                          \
            gload_lds4(s_ + 2048 + j_ * 64 + lane, d_ + 2048 + j_ * 64);        \
    } while (0)

    const int bstart = (ch == 0) ? (HALO / SPB) : 0;
    STAGE(0, bstart);
    STAGE(1, bstart + 1);
    int cur = 0;

    for (int b = bstart; b < NB; ++b, cur ^= 1) {
        if (b == NB - 1) { WAITVM0; } else { WAITVM11; }   // buf[cur] ready

        // phase-B x prefetch (issued early; older than next stage -> cheap wait)
        const bool isPB = ((b & 3) == 3) && (b >= HALO / SPB + 3);
        f2 xv0 = {0, 0}, xv1 = {0, 0}, xv2 = {0, 0};
        long g0 = 0;
        if (isPB && lane < NROWS) {
            int r = (b - (HALO / SPB + 3)) >> 2;
            g0 = cbase + (long)r * 64 + 2 * lane;
            const f2* xp = (const f2*)(x + g0 * 3);
            xv0 = xp[0]; xv1 = xp[1]; xv2 = xp[2];
        }

        // preload this block's u values into registers
        float uu0[SPB], uu1[SPB], uu2[SPB];
        const float* ub = &ubuf[cur][0];
        #pragma unroll
        for (int t = 0; t < SPB; t++) {
            uu0[t] = ub[t * 140 + lane];
            uu1[t] = ub[t * 140 + 64 + lane];
            uu2[t] = ub[t * 140 + 128 + (lane < 12 ? lane : 11)];
        }
        WAITLGKM;                       // reads retired -> safe to overwrite buf
        if (b + 2 < NB) STAGE(cur, b + 2);

        // 16 recurrence steps (3 independent chains/lane), fp16 pairs to LDS
        const int rowbase = ((b - HALO / SPB) & 3) * 8;
        #pragma unroll
        for (int t = 0; t < SPB; t += 2) {
            wa = sigstep(wa, fold(uu0[t]));
            wb = sigstep(wb, fold(uu1[t]));
            wc = sigstep(wc, fold(uu2[t]));
            float wa0 = wa, wb0 = wb, wc0 = wc;
            wa = sigstep(wa, fold(uu0[t + 1]));
            wb = sigstep(wb, fold(uu1[t + 1]));
            wc = sigstep(wc, fold(uu2[t + 1]));
            if (b >= HALO / SPB) {
                uint32_t* tw = &traj[(rowbase + (t >> 1)) * TROW + lane];
                tw[0]  = pk16(wa0, wa);
                tw[64] = pk16(wb0, wb);
                if (lane < 12) tw[128] = pk16(wc0, wc);
            }
        }

        // phase B: 64-step round done -> lanes 0..31 run 2 MLP steps packed f16
        if (isPB && lane < NROWS) {
            const uint32_t* tr_ = &traj[lane * TROW];
            h2 xq0 = pkrtz(xv0[0], xv1[1]);
            h2 xq1 = pkrtz(xv0[1], xv2[0]);
            h2 xq2 = pkrtz(xv1[0], xv2[1]);
            h2 h1[10];
            #pragma unroll
            for (int cc = 0; cc < 10; cc++) {
                h2 acc = ldw(tr_[cc]) * xq0;
                acc += ldw(tr_[10 + cc]) * xq1;
                acc += ldw(tr_[20 + cc]) * xq2;
                h1[cc] = tanh2(acc);
            }
            h2 hh[10];
            #pragma unroll
            for (int cc = 0; cc < 10; cc++) {
                h2 acc = h1[0] * ldw(tr_[30 + cc]);
                #pragma unroll
                for (int r2 = 1; r2 < 10; r2++)
                    acc += h1[r2] * ldw(tr_[30 + r2 * 10 + cc]);
                hh[cc] = tanh2(acc);
            }
            h2 ya = hh[0] * ldw(tr_[130]);
            #pragma unroll
            for (int r2 = 1; r2 < 10; r2++) ya += hh[r2] * ldw(tr_[130 + r2]);
            f2 o_; o_[0] = (float)ya[0]; o_[1] = (float)ya[1];
            *reinterpret_cast<f2*>(out + g0) = o_;
        }
    }
#undef STAGE
}

extern "C" void kernel_launch(void* const* d_in, const int* in_sizes, int n_in,
                              void* d_out, int out_size, void* d_ws, size_t ws_size,
                              hipStream_t stream) {
    const float* x  = (const float*)d_in[0];
    const float* u  = (const float*)d_in[1];
    const float* W1 = (const float*)d_in[2];
    const float* W2 = (const float*)d_in[3];
    const float* W3 = (const float*)d_in[4];
    float* out = (float*)d_out;

    hipLaunchKernelGGL(fastnet_kernel, dim3(NCH), dim3(64), 0, stream,
                       x, u, W1, W2, W3, out);
}

// Round 5
// 40.972 us; speedup vs baseline: 3.3398x; 1.0317x over previous
//
#include <hip/hip_runtime.h>
#include <hip/hip_fp16.h>

typedef _Float16 h2 __attribute__((ext_vector_type(2)));
typedef float f2 __attribute__((ext_vector_type(2)));

#define NCH   2048                 // chunks (one single-wave workgroup each)
#define CL    128                  // outputs per chunk
#define HALO  32                   // warm-up steps (contraction ~e^-182: safe)
#define SPB   8                    // steps per staged block
#define NB    ((HALO + CL) / SPB)  // 20 blocks
#define UBUF_DW (SPB * 140)        // 1120 dwords = 4x w16 + 2x w4 issues
#define TROW  141                  // traj row stride (odd -> conflict-free)
#define NROWS 16                   // pair-rows per phase-B round (32 steps)
#define BH    (HALO / SPB)         // 4 halo blocks

#if __has_builtin(__builtin_amdgcn_exp2f)
#define EXP2F __builtin_amdgcn_exp2f
#else
#define EXP2F exp2f
#endif
#if __has_builtin(__builtin_amdgcn_rcpf)
#define RCPF __builtin_amdgcn_rcpf
#else
#define RCPF(x) (1.0f / (x))
#endif

#define A_K   (-14.4269504088896341f)   /* -10*log2(e) */
#define UPC_K (7.21347520444481704f)    /* -A_K*0.5    */
#define K2_K  (2.8853900817779268f)     /* 2*log2(e)   */

__device__ __forceinline__ h2 pkrtz(float a, float b) {
    return __builtin_bit_cast(h2, __builtin_amdgcn_cvt_pkrtz(a, b));
}
__device__ __forceinline__ float sigstep(float w, float up) {
    return RCPF(1.0f + EXP2F(__builtin_fmaf(A_K, w, up)));
}
__device__ __forceinline__ float fold(float u) {
    return __builtin_fmaf(A_K, u, UPC_K);
}
__device__ __forceinline__ uint32_t pk16(float a, float b) {
    return __builtin_bit_cast(uint32_t, pkrtz(a, b));
}
__device__ __forceinline__ h2 ldw(uint32_t v) {
    return __builtin_bit_cast(h2, v);
}
__device__ __forceinline__ h2 tanh2(h2 a) {
    float z0 = (float)a[0], z1 = (float)a[1];
    float t0 = 1.0f - 2.0f * RCPF(1.0f + EXP2F(K2_K * z0));
    float t1 = 1.0f - 2.0f * RCPF(1.0f + EXP2F(K2_K * z1));
    return pkrtz(t0, t1);
}

// async global->LDS: the wave's lanes land at ldsbase + lane*size (linear)
__device__ __forceinline__ void gload_lds16(const float* g, float* l) {
    __builtin_amdgcn_global_load_lds(
        (__attribute__((address_space(1))) void*)(void*)g,
        (__attribute__((address_space(3))) void*)(void*)l, 16, 0, 0);
}
__device__ __forceinline__ void gload_lds4(const float* g, float* l) {
    __builtin_amdgcn_global_load_lds(
        (__attribute__((address_space(1))) void*)(void*)g,
        (__attribute__((address_space(3))) void*)(void*)l, 4, 0, 0);
}

#define WAITVM6  asm volatile("s_waitcnt vmcnt(6)"  ::: "memory")
#define WAITVM0  asm volatile("s_waitcnt vmcnt(0)"  ::: "memory")
#define WAITLGKM asm volatile("s_waitcnt lgkmcnt(0)" ::: "memory")

__global__ void __launch_bounds__(64)
fastnet_kernel(const float* __restrict__ x, const float* __restrict__ u,
               const float* __restrict__ W1, const float* __restrict__ W2,
               const float* __restrict__ W3, float* __restrict__ out) {
    __shared__ float    ubuf[2][UBUF_DW];     // 8.96 KB staged u, double-buffered
    __shared__ uint32_t traj[NROWS * TROW];   // 9.02 KB fp16 weight trajectory
    // total 17.98 KB -> 8 wg/CU -> grid of 2048 fully resident, 2 waves/SIMD

    const int  lane  = threadIdx.x;
    const int  ch    = blockIdx.x;
    const long cbase = (long)ch * CL;
    const float* su  = u + (cbase - (long)HALO) * 140;

    // ---- initial weights: chunk 0 exact, others converge through the halo ----
    float wa, wb, wc;
    if (ch == 0) {
        wa = (lane < 30) ? W1[lane] : (lane < 130 ? W2[lane - 30] : W3[lane - 130]);
        wb = W2[lane + 34];
        int kc = lane + 128;
        wc = (lane < 12) ? ((kc < 130) ? W2[kc - 30] : W3[kc - 130]) : 0.5f;
    } else {
        wa = wb = wc = 0.5f;
    }

    // stage one 8-step block of u into LDS buffer BUF_ (6 async vmcnt events)
#define STAGE(BUF_, B_) do {                                                    \
        const float* s_ = su + (long)(B_) * UBUF_DW;                            \
        float* d_ = &ubuf[BUF_][0];                                             \
        _Pragma("unroll")                                                       \
        for (int i_ = 0; i_ < 4; i_++)                                          \
            gload_lds16(s_ + i_ * 256 + lane * 4, d_ + i_ * 256);               \
        gload_lds4(s_ + 1024 + lane, d_ + 1024);                                \
        if (lane < 32) gload_lds4(s_ + 1088 + lane, d_ + 1088);                 \
    } while (0)

    const int bstart = (ch == 0) ? BH : 0;
    STAGE(0, bstart);
    STAGE(1, bstart + 1);
    int cur = 0;

    for (int b = bstart; b < NB; ++b, cur ^= 1) {
        if (b == NB - 1) { WAITVM0; } else { WAITVM6; }   // buf[cur] ready

        // phase-B x prefetch: issued BEFORE next stage so vmcnt(6) count stays exact
        const bool isPB = ((b & 3) == 3) && (b >= BH + 3);
        f2 xv0 = {0, 0}, xv1 = {0, 0}, xv2 = {0, 0};
        long g0 = 0;
        if (isPB && lane < NROWS) {
            int r = (b - (BH + 3)) >> 2;
            g0 = cbase + (long)r * (2 * NROWS) + 2 * lane;
            const f2* xp = (const f2*)(x + g0 * 3);
            xv0 = xp[0]; xv1 = xp[1]; xv2 = xp[2];
        }

        // preload this block's u values into registers
        float uu0[SPB], uu1[SPB], uu2[SPB];
        const float* ub = &ubuf[cur][0];
        #pragma unroll
        for (int t = 0; t < SPB; t++) {
            uu0[t] = ub[t * 140 + lane];
            uu1[t] = ub[t * 140 + 64 + lane];
            uu2[t] = ub[t * 140 + 128 + (lane < 12 ? lane : 11)];
        }
        WAITLGKM;                       // reads retired -> safe to overwrite buf
        if (b + 2 < NB) STAGE(cur, b + 2);

        // 8 recurrence steps (3 independent chains/lane), fp16 pairs to LDS
        const int rowbase = ((b - BH) & 3) * (SPB / 2);
        #pragma unroll
        for (int t = 0; t < SPB; t += 2) {
            wa = sigstep(wa, fold(uu0[t]));
            wb = sigstep(wb, fold(uu1[t]));
            wc = sigstep(wc, fold(uu2[t]));
            float wa0 = wa, wb0 = wb, wc0 = wc;
            wa = sigstep(wa, fold(uu0[t + 1]));
            wb = sigstep(wb, fold(uu1[t + 1]));
            wc = sigstep(wc, fold(uu2[t + 1]));
            if (b >= BH) {
                uint32_t* tw = &traj[(rowbase + (t >> 1)) * TROW + lane];
                tw[0]  = pk16(wa0, wa);
                tw[64] = pk16(wb0, wb);
                if (lane < 12) tw[128] = pk16(wc0, wc);
            }
        }

        // phase B: 32-step round done -> lanes 0..15 run 2 MLP steps packed f16
        if (isPB && lane < NROWS) {
            const uint32_t* tr_ = &traj[lane * TROW];
            h2 xq0 = pkrtz(xv0[0], xv1[1]);
            h2 xq1 = pkrtz(xv0[1], xv2[0]);
            h2 xq2 = pkrtz(xv1[0], xv2[1]);
            h2 h1[10];
            #pragma unroll
            for (int cc = 0; cc < 10; cc++) {
                h2 acc = ldw(tr_[cc]) * xq0;
                acc += ldw(tr_[10 + cc]) * xq1;
                acc += ldw(tr_[20 + cc]) * xq2;
                h1[cc] = tanh2(acc);
            }
            h2 hh[10];
            #pragma unroll
            for (int cc = 0; cc < 10; cc++) {
                h2 acc = h1[0] * ldw(tr_[30 + cc]);
                #pragma unroll
                for (int r2 = 1; r2 < 10; r2++)
                    acc += h1[r2] * ldw(tr_[30 + r2 * 10 + cc]);
                hh[cc] = tanh2(acc);
            }
            h2 ya = hh[0] * ldw(tr_[130]);
            #pragma unroll
            for (int r2 = 1; r2 < 10; r2++) ya += hh[r2] * ldw(tr_[130 + r2]);
            f2 o_; o_[0] = (float)ya[0]; o_[1] = (float)ya[1];
            *reinterpret_cast<f2*>(out + g0) = o_;
        }
    }
#undef STAGE
}

extern "C" void kernel_launch(void* const* d_in, const int* in_sizes, int n_in,
                              void* d_out, int out_size, void* d_ws, size_t ws_size,
                              hipStream_t stream) {
    const float* x  = (const float*)d_in[0];
    const float* u  = (const float*)d_in[1];
    const float* W1 = (const float*)d_in[2];
    const float* W2 = (const float*)d_in[3];
    const float* W3 = (const float*)d_in[4];
    float* out = (float*)d_out;

    hipLaunchKernelGGL(fastnet_kernel, dim3(NCH), dim3(64), 0, stream,
                       x, u, W1, W2, W3, out);
}